// Round 11
// baseline (2519.568 us; speedup 1.0000x reference)
//
#include <hip/hip_runtime.h>
#include <stdint.h>

// ---------------------------------------------------------------------------
// TContrastive: GRACE InfoNCE loss.
//   loss_view = (1/2N) sum_i log(S_i - e^2) - (2/N) sum_i g12_i
// where S = row sums of exp(2 * M M^T), M = [n1; n2] row-normalized (16384x1024).
// Heavy GEMMs in bf16 MFMA, fp32 accumulate. tau = 0.5.
// R1: Gram symmetry — triangle tiles only; off-diag adds row+col exp-sums.
// R2-R10 lessons (8 structural variants, all 620-694 TF on the gram):
//   - Read-swizzles, XCD swizzle, 4/8-phase schedules, counted vmcnt, 32x32
//     shape, multi-block residency: all flat or regressive.
//   - R10 decisive: 4 independent blocks/CU, 0 conflicts, still 27% MfmaUtil.
//     ~600 cyc/K-tile of syncthreads-drained staging latency serializes every
//     block; the stage->barrier->read paradigm itself is the wall.
// R11: NO-LDS gram (Common-mistake #7: H = 33.5MB is L2/L3-resident; staging
//     cache-fit data is pure overhead). Fragments load directly global->VGPR:
//     8 dwordx4 loads/wave/K-tile, zero barriers, zero DMA, zero LDS. Latency
//     hidden by TLP: launch_bounds(256,4) -> <=128 VGPR -> 4 waves/SIMD, all
//     independent. Unique bytes/block/K-tile unchanged (16KB) -> same L2 load.
//     32x32x16 MFMA (R7/R8-verified fragment mapping + epilogue).
// ---------------------------------------------------------------------------

typedef unsigned short u16;
typedef __attribute__((ext_vector_type(8))) __bf16 bf16x8;
typedef __attribute__((ext_vector_type(4))) float f32x4;
typedef __attribute__((ext_vector_type(16))) float f32x16;

#define NS 8192       // samples per view half
#define DD 1024       // feature dim

__device__ __forceinline__ float bf2f(u16 u) {
    union { uint32_t i; float f; } v; v.i = ((uint32_t)u) << 16; return v.f;
}
__device__ __forceinline__ u16 f2bf(float f) {
    union { float f; uint32_t i; } v; v.f = f;
    return (u16)((v.i + 0x7FFFu + ((v.i >> 16) & 1u)) >> 16);   // RNE
}

// async global->LDS, 16B per lane. LDS dest must be wave-uniform-base + lane*16.
__device__ __forceinline__ void gload16(const u16* g, u16* l) {
    __builtin_amdgcn_global_load_lds(
        (__attribute__((address_space(1))) void*)(uintptr_t)(g),
        (__attribute__((address_space(3))) void*)(uintptr_t)(l), 16, 0, 0);
}

// ---------------- elementwise conversion kernels ----------------

__global__ __launch_bounds__(256) void conv_f2bf(const float* __restrict__ src,
                                                 u16* __restrict__ dst) {
    int i = (blockIdx.x * 256 + threadIdx.x) * 4;
    float4 v = *(const float4*)(src + i);
    ushort4 o;
    o.x = f2bf(v.x); o.y = f2bf(v.y); o.z = f2bf(v.z); o.w = f2bf(v.w);
    *(ushort4*)(dst + i) = o;
}

// Z = bf16([ta; tb]) row view (16384x1024), 16384 blocks
__global__ __launch_bounds__(256) void conv_cat(const float* __restrict__ a,
                                                const float* __restrict__ b,
                                                u16* __restrict__ Z) {
    size_t i = (size_t)(blockIdx.x * 256 + threadIdx.x) * 4;
    const size_t half = (size_t)NS * DD;
    const float* s = (i < half) ? (a + i) : (b + (i - half));
    float4 v = *(const float4*)s;
    ushort4 o;
    o.x = f2bf(v.x); o.y = f2bf(v.y); o.z = f2bf(v.z); o.w = f2bf(v.w);
    *(ushort4*)(Z + i) = o;
}

// column view: Z[i, b*32+a] = src[i, a*32+b]  (per-row 32x32 transpose)
__global__ __launch_bounds__(256) void conv_col(const float* __restrict__ a,
                                                const float* __restrict__ b,
                                                u16* __restrict__ Z) {
    size_t i = (size_t)(blockIdx.x * 256 + threadIdx.x) * 4;
    const size_t half = (size_t)NS * DD;
    const float* src; size_t o;
    if (i < half) { src = a; o = i; } else { src = b; o = i - half; }
    size_t row = o >> 10;
    int j = (int)(o & 1023);
    int aI = j & 31, bI = j >> 5;      // j = b*32 + a
    const float* rp = src + (row << 10);
    ushort4 ov;
    ov.x = f2bf(rp[aI * 32 + bI]);
    ov.y = f2bf(rp[(aI + 1) * 32 + bI]);
    ov.z = f2bf(rp[(aI + 2) * 32 + bI]);
    ov.w = f2bf(rp[(aI + 3) * 32 + bI]);
    *(ushort4*)(Z + i) = ov;
}

// ---------------- fc GEMM: C[m,n] = sum_k A[m,k] * B[n,k] (128^2 tile path)
// MODE 0: out = bf16(elu(C + bias))      (fc_a)
// MODE 1: out = bf16(C + bias)           (fc_b)
template <int MODE>
__global__ __launch_bounds__(256) void gemm_bt(const u16* A, const u16* B,
                                               const float* __restrict__ bias,
                                               u16* __restrict__ out) {
    __shared__ alignas(16) u16 As[128 * 32];
    __shared__ alignas(16) u16 Bs[128 * 32];
    const int tid = threadIdx.x;

    const int tm = blockIdx.y, tn = blockIdx.x;
    const size_t tileM = (size_t)tm * 128;
    const size_t tileN = (size_t)tn * 128;

    const int csw = ((tid & 3) ^ ((tid >> 4) & 3)) * 8;
    const u16* gA0 = A + (tileM + (tid >> 2)) * DD + csw;
    const u16* gA1 = gA0 + (size_t)64 * DD;
    const u16* gB0 = B + (tileN + (tid >> 2)) * DD + csw;
    const u16* gB1 = gB0 + (size_t)64 * DD;
    u16* lA0 = &As[tid * 8]; u16* lA1 = lA0 + 2048;
    u16* lB0 = &Bs[tid * 8]; u16* lB1 = lB0 + 2048;

    const int lane = tid & 63;
    const int wv = tid >> 6;
    const int wr = (wv >> 1) << 6;
    const int wc = (wv & 1) << 6;
    const int lr = lane & 15;
    const int lh = lane >> 4;
    const int sw = lh ^ ((lr >> 2) & 3);

    const u16* aBase = &As[(wr + lr) * 32 + sw * 8];
    const u16* bBase = &Bs[(wc + lr) * 32 + sw * 8];

    f32x4 acc[4][4];
#pragma unroll
    for (int i = 0; i < 4; i++)
#pragma unroll
        for (int j = 0; j < 4; j++) acc[i][j] = (f32x4)0.0f;

    for (int k0 = 0; k0 < DD; k0 += 32) {
        gload16(gA0 + k0, lA0);
        gload16(gA1 + k0, lA1);
        gload16(gB0 + k0, lB0);
        gload16(gB1 + k0, lB1);
        __syncthreads();
        bf16x8 af[4], bfr[4];
#pragma unroll
        for (int rt = 0; rt < 4; rt++) af[rt] = *(const bf16x8*)(aBase + rt * 512);
#pragma unroll
        for (int ct = 0; ct < 4; ct++) bfr[ct] = *(const bf16x8*)(bBase + ct * 512);
#pragma unroll
        for (int rt = 0; rt < 4; rt++)
#pragma unroll
            for (int ct = 0; ct < 4; ct++)
                acc[rt][ct] = __builtin_amdgcn_mfma_f32_16x16x32_bf16(
                    af[rt], bfr[ct], acc[rt][ct], 0, 0, 0);
        __syncthreads();
    }

    float bcol[4];
#pragma unroll
    for (int ct = 0; ct < 4; ct++) bcol[ct] = bias[tileN + wc + ct * 16 + lr];
#pragma unroll
    for (int rt = 0; rt < 4; rt++) {
#pragma unroll
        for (int r = 0; r < 4; r++) {
            size_t row = tileM + wr + rt * 16 + lh * 4 + r;
            u16* orow = out + row * DD + tileN + wc + lr;
#pragma unroll
            for (int ct = 0; ct < 4; ct++) {
                float v = acc[rt][ct][r] + bcol[ct];
                if (MODE == 0) v = v > 0.0f ? v : expm1f(v);
                orow[ct * 16] = f2bf(v);
            }
        }
    }
}

// ---------------- Gram kernel: NO-LDS direct-load, 32x32x16 MFMA ---------
// 128^2 block tile, 4 waves (2x2 of 64x64), fragments loaded global->VGPR
// (H is L2/L3-resident). Zero barriers; TLP (4 waves/SIMD) hides L2 latency.
// Triangle grid dim3(129, 64) = 8256 blocks (tm <= tn).
// S[row] += exp-row-sums; off-diag tiles also S[col] += exp-col-sums.
__global__ __launch_bounds__(256, 4) void gram128(const u16* __restrict__ H,
                                                  float* __restrict__ S) {
    const int tid = threadIdx.x;

    int x = blockIdx.x, y = blockIdx.y;      // x in [0,129), y in [0,64)
    int tm, tn;
    if (y + x < 128) { tm = y;       tn = y + x; }
    else             { tm = 127 - y; tn = x - 1; }
    const size_t rowA = (size_t)tm * 128;
    const size_t rowB = (size_t)tn * 128;

    // MFMA indexing: 4 waves = 2x2, per-wave 64x64 = 2x2 tiles of 32x32.
    // Fragment (32x32x16): lane reads row = base + (lane&31), k = (lane>>5)*8+j.
    // kk=0 -> cols [k0 + hi*8, +8);  kk=1 -> cols [k0+16 + hi*8, +8).
    // Per K-tile each 64B row-segment is consumed exactly once across the wave.
    const int lane = tid & 63;
    const int wv = tid >> 6;
    const int wr = (wv >> 1) * 64;           // 0 / 64
    const int wc = (wv & 1) * 64;            // 0 / 64
    const int c31 = lane & 31;
    const int hi  = lane >> 5;

    const u16* pA = H + (rowA + wr + c31) * (size_t)DD + hi * 8;
    const u16* pB = H + (rowB + wc + c31) * (size_t)DD + hi * 8;

    f32x16 acc[2][2];
#pragma unroll
    for (int i = 0; i < 2; ++i)
#pragma unroll
        for (int j = 0; j < 2; ++j) acc[i][j] = (f32x16)0.0f;

    for (int k0 = 0; k0 < DD; k0 += 32) {
        bf16x8 fA[2][2], fB[2][2];
#pragma unroll
        for (int mt = 0; mt < 2; ++mt)
#pragma unroll
            for (int kk = 0; kk < 2; ++kk) {
                fA[mt][kk] = *(const bf16x8*)(pA + (size_t)mt * 32 * DD + k0 + kk * 16);
                fB[mt][kk] = *(const bf16x8*)(pB + (size_t)mt * 32 * DD + k0 + kk * 16);
            }
#pragma unroll
        for (int mt = 0; mt < 2; ++mt)
#pragma unroll
            for (int nt = 0; nt < 2; ++nt)
#pragma unroll
                for (int kk = 0; kk < 2; ++kk)
                    acc[mt][nt] = __builtin_amdgcn_mfma_f32_32x32x16_bf16(
                        fA[mt][kk], fB[nt][kk], acc[mt][nt], 0, 0, 0);
    }

    // epilogue: exp + row sums (always) + col sums (off-diag symmetry).
    // 32x32 C layout: col = lane&31, row = (j&3) + 8*(j>>2) + 4*(lane>>5).
    const bool offdiag = (tm != tn);
    float csum[2] = {0.f, 0.f};
#pragma unroll
    for (int mt = 0; mt < 2; ++mt) {
#pragma unroll
        for (int j = 0; j < 16; ++j) {
            float rs = 0.0f;
#pragma unroll
            for (int nt = 0; nt < 2; ++nt) {
                float e = __expf(2.0f * acc[mt][nt][j]);
                rs += e;
                csum[nt] += e;
            }
            rs += __shfl_xor(rs, 1);
            rs += __shfl_xor(rs, 2);
            rs += __shfl_xor(rs, 4);
            rs += __shfl_xor(rs, 8);
            rs += __shfl_xor(rs, 16);
            if (c31 == 0) {
                size_t row = rowA + wr + mt * 32 + (j & 3) + 8 * (j >> 2) + 4 * hi;
                atomicAdd(&S[row], rs);
            }
        }
    }
    if (offdiag) {
#pragma unroll
        for (int nt = 0; nt < 2; ++nt) {
            float cs = csum[nt];
            cs += __shfl_xor(cs, 32);      // merge the two row-halves
            if (hi == 0) {
                size_t col = rowB + wc + nt * 32 + c31;
                atomicAdd(&S[col], cs);
            }
        }
    }
}

// row-normalize bf16 matrix in place (one block per row of 1024)
__global__ __launch_bounds__(256) void normalize_kernel(u16* M) {
    __shared__ float red[4];
    const int tid = threadIdx.x;
    u16* row = M + ((size_t)blockIdx.x << 10);
    ushort4 v = ((const ushort4*)row)[tid];
    float x0 = bf2f(v.x), x1 = bf2f(v.y), x2 = bf2f(v.z), x3 = bf2f(v.w);
    float s = x0 * x0 + x1 * x1 + x2 * x2 + x3 * x3;
#pragma unroll
    for (int m = 1; m < 64; m <<= 1) s += __shfl_xor(s, m);
    if ((tid & 63) == 0) red[tid >> 6] = s;
    __syncthreads();
    float inv = rsqrtf(red[0] + red[1] + red[2] + red[3]);
    ushort4 o;
    o.x = f2bf(x0 * inv); o.y = f2bf(x1 * inv);
    o.z = f2bf(x2 * inv); o.w = f2bf(x3 * inv);
    ((ushort4*)row)[tid] = o;
}

// g12[i] = dot(M[i], M[i+NS])  (one block per i)
__global__ __launch_bounds__(256) void diag_kernel(const u16* M, float* g12) {
    __shared__ float red[4];
    const int tid = threadIdx.x;
    const u16* r1 = M + ((size_t)blockIdx.x << 10);
    const u16* r2 = r1 + ((size_t)NS << 10);
    ushort4 a = ((const ushort4*)r1)[tid];
    ushort4 b = ((const ushort4*)r2)[tid];
    float s = bf2f(a.x) * bf2f(b.x) + bf2f(a.y) * bf2f(b.y) +
              bf2f(a.z) * bf2f(b.z) + bf2f(a.w) * bf2f(b.w);
#pragma unroll
    for (int m = 1; m < 64; m <<= 1) s += __shfl_xor(s, m);
    if ((tid & 63) == 0) red[tid >> 6] = s;
    __syncthreads();
    if (tid == 0) g12[blockIdx.x] = red[0] + red[1] + red[2] + red[3];
}

__global__ __launch_bounds__(256) void final_kernel(const float* Sr, const float* Sc,
                                                    const float* gr, const float* gc,
                                                    const float* w_r1, float* out) {
    __shared__ float red[16];
    const float E2 = 7.389056098930650f;  // exp(1/tau), tau=0.5
    float a = 0.f, b = 0.f, c = 0.f, d = 0.f;
    for (int i = threadIdx.x; i < 2 * NS; i += 256) {
        a += logf(Sr[i] - E2);
        b += logf(Sc[i] - E2);
    }
    for (int i = threadIdx.x; i < NS; i += 256) {
        c += gr[i];
        d += gc[i];
    }
#pragma unroll
    for (int m = 1; m < 64; m <<= 1) {
        a += __shfl_xor(a, m); b += __shfl_xor(b, m);
        c += __shfl_xor(c, m); d += __shfl_xor(d, m);
    }
    int w = threadIdx.x >> 6;
    if ((threadIdx.x & 63) == 0) {
        red[w] = a; red[4 + w] = b; red[8 + w] = c; red[12 + w] = d;
    }
    __syncthreads();
    if (threadIdx.x == 0) {
        a = red[0] + red[1] + red[2] + red[3];
        b = red[4] + red[5] + red[6] + red[7];
        c = red[8] + red[9] + red[10] + red[11];
        d = red[12] + red[13] + red[14] + red[15];
        float lr = a / (2.0f * NS) - 2.0f * c / NS;
        float lc = b / (2.0f * NS) - 2.0f * d / NS;
        float w0 = w_r1[0];
        w0 = fminf(fmaxf(w0, 0.0f), 1.0f);
        out[0] = w0 * lr + (1.0f - w0) * lc;
    }
}

extern "C" void kernel_launch(void* const* d_in, const int* in_sizes, int n_in,
                              void* d_out, int out_size, void* d_ws, size_t ws_size,
                              hipStream_t stream) {
    const float* ta = (const float*)d_in[0];
    const float* tb = (const float*)d_in[1];
    const float* W1 = (const float*)d_in[2];
    const float* b1 = (const float*)d_in[3];
    const float* W2 = (const float*)d_in[4];
    const float* b2 = (const float*)d_in[5];
    const float* W3 = (const float*)d_in[6];
    const float* b3 = (const float*)d_in[7];
    const float* W4 = (const float*)d_in[8];
    const float* b4 = (const float*)d_in[9];
    const float* wr = (const float*)d_in[10];
    float* out = (float*)d_out;

    char* p = (char*)d_ws;
    const size_t MAT = (size_t)2 * NS * DD * sizeof(u16);  // 33.5 MB
    u16* Z = (u16*)p;  p += MAT;
    u16* T = (u16*)p;  p += MAT;
    u16* H = (u16*)p;  p += MAT;
    u16* Wb = (u16*)p; p += (size_t)4 * DD * DD * sizeof(u16);
    float* Sr = (float*)p;  p += 2 * NS * sizeof(float);
    float* Sc = (float*)p;  p += 2 * NS * sizeof(float);
    float* gr = (float*)p;  p += NS * sizeof(float);
    float* gc = (float*)p;  p += NS * sizeof(float);

    u16* Wb1 = Wb;
    u16* Wb2 = Wb + (size_t)DD * DD;
    u16* Wb3 = Wb + (size_t)2 * DD * DD;
    u16* Wb4 = Wb + (size_t)3 * DD * DD;

    conv_f2bf<<<1024, 256, 0, stream>>>(W1, Wb1);
    conv_f2bf<<<1024, 256, 0, stream>>>(W2, Wb2);
    conv_f2bf<<<1024, 256, 0, stream>>>(W3, Wb3);
    conv_f2bf<<<1024, 256, 0, stream>>>(W4, Wb4);
    hipMemsetAsync(Sr, 0, 4 * NS * sizeof(float), stream);  // Sr and Sc contiguous

    // ---- row view ----
    conv_cat<<<16384, 256, 0, stream>>>(ta, tb, Z);
    gemm_bt<0><<<dim3(8, 128), 256, 0, stream>>>(Z, Wb1, b1, T);
    gemm_bt<1><<<dim3(8, 128), 256, 0, stream>>>(T, Wb2, b2, H);
    normalize_kernel<<<16384, 256, 0, stream>>>(H);
    diag_kernel<<<8192, 256, 0, stream>>>(H, gr);
    gram128<<<dim3(129, 64), 256, 0, stream>>>(H, Sr);

    // ---- column view ----
    conv_col<<<16384, 256, 0, stream>>>(ta, tb, Z);
    gemm_bt<0><<<dim3(8, 128), 256, 0, stream>>>(Z, Wb3, b3, T);
    gemm_bt<1><<<dim3(8, 128), 256, 0, stream>>>(T, Wb4, b4, H);
    normalize_kernel<<<16384, 256, 0, stream>>>(H);
    diag_kernel<<<8192, 256, 0, stream>>>(H, gc);
    gram128<<<dim3(129, 64), 256, 0, stream>>>(H, Sc);

    final_kernel<<<1, 256, 0, stream>>>(Sr, Sc, gr, gc, wr, out);
}

// Round 12
// 1123.501 us; speedup vs baseline: 2.2426x; 2.2426x over previous
//
#include <hip/hip_runtime.h>
#include <stdint.h>

// ---------------------------------------------------------------------------
// TContrastive: GRACE InfoNCE loss.
//   loss_view = (1/2N) sum_i log(S_i - e^2) - (2/N) sum_i g12_i
// where S = row sums of exp(2 * M M^T), M = [n1; n2] row-normalized (16384x1024).
// Heavy GEMMs in bf16 MFMA (16x16x32), fp32 accumulate. tau = 0.5.
// R1: Gram symmetry — triangle tiles only; off-diag adds row+col exp-sums.
// R2-R11 ledger (9 gram variants):
//   - staged variants plateau 620-694 TF; R4 (256^2, ring-4, 1 barrier/K-tile,
//     counted vmcnt) best at 412us/view. Falsified levers: read swizzles,
//     XCD remap (FETCH +55%), 4/8-phase schedules, 32x32 shape in 8-wave cfg,
//     multi-block residency (458us), NO-LDS direct load (1090us, latency).
//   - Staging latency through the barrier is the structural cost; paradigm
//     survives all alternatives tested.
// R12: keep R4 gram internals EXACTLY; remove measured dead time around it:
//   (1) both view-grams in ONE dispatch (tail 2x10.8% -> 1x4.6%, ~45us);
//       Hc aliased into freed Z buffer (R7-proven).
//   (2) normalize+diag fused (one pass over H; dot uses rounded bf16 ->
//       numerics identical to the split kernels).
//   (3) 4x conv_f2bf batched into one launch.
// ---------------------------------------------------------------------------

typedef unsigned short u16;
typedef __attribute__((ext_vector_type(8))) __bf16 bf16x8;
typedef __attribute__((ext_vector_type(4))) float f32x4;

#define NS 8192       // samples per view half
#define DD 1024       // feature dim

__device__ __forceinline__ float bf2f(u16 u) {
    union { uint32_t i; float f; } v; v.i = ((uint32_t)u) << 16; return v.f;
}
__device__ __forceinline__ u16 f2bf(float f) {
    union { float f; uint32_t i; } v; v.f = f;
    return (u16)((v.i + 0x7FFFu + ((v.i >> 16) & 1u)) >> 16);   // RNE
}

// async global->LDS, 16B per lane. LDS dest must be wave-uniform-base + lane*16.
__device__ __forceinline__ void gload16(const u16* g, u16* l) {
    __builtin_amdgcn_global_load_lds(
        (__attribute__((address_space(1))) void*)(uintptr_t)(g),
        (__attribute__((address_space(3))) void*)(uintptr_t)(l), 16, 0, 0);
}

// ---------------- elementwise conversion kernels ----------------

// all 4 weight matrices in one launch: 4096 blocks, 1024 floats each
__global__ __launch_bounds__(256) void conv_f2bf4(const float* __restrict__ W1,
                                                  const float* __restrict__ W2,
                                                  const float* __restrict__ W3,
                                                  const float* __restrict__ W4,
                                                  u16* __restrict__ dst) {
    const int b = blockIdx.x;                 // [0,4096)
    const float* src = (b < 1024) ? W1 : (b < 2048) ? W2 : (b < 3072) ? W3 : W4;
    const size_t so = ((size_t)(b & 1023) << 10) + threadIdx.x * 4;
    const size_t dо = ((size_t)b << 10) + threadIdx.x * 4;
    float4 v = *(const float4*)(src + so);
    ushort4 o;
    o.x = f2bf(v.x); o.y = f2bf(v.y); o.z = f2bf(v.z); o.w = f2bf(v.w);
    *(ushort4*)(dst + dо) = o;
}

// Z = bf16([ta; tb]) row view (16384x1024), 16384 blocks
__global__ __launch_bounds__(256) void conv_cat(const float* __restrict__ a,
                                                const float* __restrict__ b,
                                                u16* __restrict__ Z) {
    size_t i = (size_t)(blockIdx.x * 256 + threadIdx.x) * 4;
    const size_t half = (size_t)NS * DD;
    const float* s = (i < half) ? (a + i) : (b + (i - half));
    float4 v = *(const float4*)s;
    ushort4 o;
    o.x = f2bf(v.x); o.y = f2bf(v.y); o.z = f2bf(v.z); o.w = f2bf(v.w);
    *(ushort4*)(Z + i) = o;
}

// column view: Z[i, b*32+a] = src[i, a*32+b]  (per-row 32x32 transpose)
__global__ __launch_bounds__(256) void conv_col(const float* __restrict__ a,
                                                const float* __restrict__ b,
                                                u16* __restrict__ Z) {
    size_t i = (size_t)(blockIdx.x * 256 + threadIdx.x) * 4;
    const size_t half = (size_t)NS * DD;
    const float* src; size_t o;
    if (i < half) { src = a; o = i; } else { src = b; o = i - half; }
    size_t row = o >> 10;
    int j = (int)(o & 1023);
    int aI = j & 31, bI = j >> 5;      // j = b*32 + a
    const float* rp = src + (row << 10);
    ushort4 ov;
    ov.x = f2bf(rp[aI * 32 + bI]);
    ov.y = f2bf(rp[(aI + 1) * 32 + bI]);
    ov.z = f2bf(rp[(aI + 2) * 32 + bI]);
    ov.w = f2bf(rp[(aI + 3) * 32 + bI]);
    *(ushort4*)(Z + i) = ov;
}

// ---------------- fc GEMM: C[m,n] = sum_k A[m,k] * B[n,k] (128^2 tile path)
// MODE 0: out = bf16(elu(C + bias))      (fc_a)
// MODE 1: out = bf16(C + bias)           (fc_b)
template <int MODE>
__global__ __launch_bounds__(256) void gemm_bt(const u16* A, const u16* B,
                                               const float* __restrict__ bias,
                                               u16* __restrict__ out) {
    __shared__ alignas(16) u16 As[128 * 32];
    __shared__ alignas(16) u16 Bs[128 * 32];
    const int tid = threadIdx.x;

    const int tm = blockIdx.y, tn = blockIdx.x;
    const size_t tileM = (size_t)tm * 128;
    const size_t tileN = (size_t)tn * 128;

    const int csw = ((tid & 3) ^ ((tid >> 4) & 3)) * 8;
    const u16* gA0 = A + (tileM + (tid >> 2)) * DD + csw;
    const u16* gA1 = gA0 + (size_t)64 * DD;
    const u16* gB0 = B + (tileN + (tid >> 2)) * DD + csw;
    const u16* gB1 = gB0 + (size_t)64 * DD;
    u16* lA0 = &As[tid * 8]; u16* lA1 = lA0 + 2048;
    u16* lB0 = &Bs[tid * 8]; u16* lB1 = lB0 + 2048;

    const int lane = tid & 63;
    const int wv = tid >> 6;
    const int wr = (wv >> 1) << 6;
    const int wc = (wv & 1) << 6;
    const int lr = lane & 15;
    const int lh = lane >> 4;
    const int sw = lh ^ ((lr >> 2) & 3);

    const u16* aBase = &As[(wr + lr) * 32 + sw * 8];
    const u16* bBase = &Bs[(wc + lr) * 32 + sw * 8];

    f32x4 acc[4][4];
#pragma unroll
    for (int i = 0; i < 4; i++)
#pragma unroll
        for (int j = 0; j < 4; j++) acc[i][j] = (f32x4)0.0f;

    for (int k0 = 0; k0 < DD; k0 += 32) {
        gload16(gA0 + k0, lA0);
        gload16(gA1 + k0, lA1);
        gload16(gB0 + k0, lB0);
        gload16(gB1 + k0, lB1);
        __syncthreads();
        bf16x8 af[4], bfr[4];
#pragma unroll
        for (int rt = 0; rt < 4; rt++) af[rt] = *(const bf16x8*)(aBase + rt * 512);
#pragma unroll
        for (int ct = 0; ct < 4; ct++) bfr[ct] = *(const bf16x8*)(bBase + ct * 512);
#pragma unroll
        for (int rt = 0; rt < 4; rt++)
#pragma unroll
            for (int ct = 0; ct < 4; ct++)
                acc[rt][ct] = __builtin_amdgcn_mfma_f32_16x16x32_bf16(
                    af[rt], bfr[ct], acc[rt][ct], 0, 0, 0);
        __syncthreads();
    }

    float bcol[4];
#pragma unroll
    for (int ct = 0; ct < 4; ct++) bcol[ct] = bias[tileN + wc + ct * 16 + lr];
#pragma unroll
    for (int rt = 0; rt < 4; rt++) {
#pragma unroll
        for (int r = 0; r < 4; r++) {
            size_t row = tileM + wr + rt * 16 + lh * 4 + r;
            u16* orow = out + row * DD + tileN + wc + lr;
#pragma unroll
            for (int ct = 0; ct < 4; ct++) {
                float v = acc[rt][ct][r] + bcol[ct];
                if (MODE == 0) v = v > 0.0f ? v : expm1f(v);
                orow[ct * 16] = f2bf(v);
            }
        }
    }
}

// ---------------- Merged Gram kernel: R4 internals, both views -----------
// 256^2 tiles, 8 waves, BK=32, 4-deep LDS ring, one barrier per K-tile,
// counted vmcnt, 16x16x32 MFMA. Grid dim3(65, 64): y<32 = row view
// (Hr -> Sbase), y>=32 = col view (Hc -> Sbase+2NS). 4160 blocks total.
__global__ __launch_bounds__(512, 2) void gram256(const u16* __restrict__ Hr,
                                                  const u16* __restrict__ Hc,
                                                  float* __restrict__ Sbase) {
    __shared__ alignas(16) u16 LA[4][256 * 32];
    __shared__ alignas(16) u16 LB[4][256 * 32];
    const int tid = threadIdx.x;

    const int view = (int)blockIdx.y >> 5;
    const u16* H = view ? Hc : Hr;
    float* S = Sbase + view * 2 * NS;
    int x = blockIdx.x, y = (int)blockIdx.y & 31;   // x in [0,65), y in [0,32)
    int tm, tn;
    if (y + x < 64) { tm = y;      tn = y + x; }
    else            { tm = 63 - y; tn = x - 1; }

    const size_t rowA = (size_t)tm * 256;
    const size_t rowB = (size_t)tn * 256;

    // staging: per K-tile, 4 units of 8KB. LDS dest LINEAR (tid*16B); global
    // source col slot swizzled by (row>>2)&3 so that
    //   LDS[row][s] = G[row][k0 + (s ^ ((row>>2)&3))*8 ..]
    const int r_lo = tid >> 2;                      // 0..127
    const int csw  = ((tid & 3) ^ ((r_lo >> 2) & 3)) * 8;
    const u16* gA0 = H + (rowA + r_lo) * DD + csw;
    const u16* gA1 = H + (rowA + 128 + r_lo) * DD + csw;
    const u16* gB0 = H + (rowB + r_lo) * DD + csw;
    const u16* gB1 = H + (rowB + 128 + r_lo) * DD + csw;
    const int ldst = tid * 8;                       // u16 offset of chunk

    // MFMA indexing: 8 waves = 2M x 4N; per-wave output 128x64.
    const int lane = tid & 63;
    const int wv = tid >> 6;
    const int wr = (wv >> 2) * 128;          // wave row offset: 0 / 128
    const int wc = (wv & 3) * 64;            // wave col offset: 0/64/128/192
    const int lr = lane & 15;
    const int lh = lane >> 4;
    const int sw = lh ^ ((lr >> 2) & 3);     // swizzled read slot
    const int aoff = (wr + lr) * 32 + sw * 8;
    const int boff = (wc + lr) * 32 + sw * 8;

    f32x4 acc[8][4];
#pragma unroll
    for (int i = 0; i < 8; ++i)
#pragma unroll
        for (int j = 0; j < 4; ++j) acc[i][j] = (f32x4)0.0f;

    // prologue: stage K-tiles 0,1,2 (12 gloads/thread)
#pragma unroll
    for (int t = 0; t < 3; ++t) {
        const int k0 = t * 32;
        gload16(gA0 + k0, &LA[t][0] + ldst);
        gload16(gA1 + k0, &LA[t][4096] + ldst);
        gload16(gB0 + k0, &LB[t][0] + ldst);
        gload16(gB1 + k0, &LB[t][4096] + ldst);
    }

    // main loop: one barrier per K-tile. Stage(t+3) targets slot (t-1)&3 —
    // safe: all waves past the barrier drained their tile-(t-1) ds_reads.
    // vmcnt gate: 4 gloads/tile; tiles t+1,t+2 (8 loads) stay in flight.
    for (int t = 0; t < 32; ++t) {
        if (t < 30)       asm volatile("s_waitcnt vmcnt(8)" ::: "memory");
        else if (t == 30) asm volatile("s_waitcnt vmcnt(4)" ::: "memory");
        else              asm volatile("s_waitcnt vmcnt(0)" ::: "memory");
        __builtin_amdgcn_s_barrier();
        asm volatile("" ::: "memory");       // pin ds_reads after barrier

        const int buf = t & 3;
        const u16* la = &LA[buf][0];
        const u16* lb = &LB[buf][0];

        bf16x8 bF[4], aF[8];
#pragma unroll
        for (int i = 0; i < 4; ++i) bF[i] = *(const bf16x8*)(lb + boff + i * 512);
#pragma unroll
        for (int i = 0; i < 8; ++i) aF[i] = *(const bf16x8*)(la + aoff + i * 512);

        if (t < 29) {
            const int nbuf = (t + 3) & 3;
            const int k0n = (t + 3) * 32;
            gload16(gA0 + k0n, &LA[nbuf][0] + ldst);
            gload16(gA1 + k0n, &LA[nbuf][4096] + ldst);
            gload16(gB0 + k0n, &LB[nbuf][0] + ldst);
            gload16(gB1 + k0n, &LB[nbuf][4096] + ldst);
        }

        __builtin_amdgcn_s_setprio(1);
#pragma unroll
        for (int mi = 0; mi < 8; ++mi)       // cluster mi gated when aF[mi] lands
#pragma unroll
            for (int ni = 0; ni < 4; ++ni)
                acc[mi][ni] = __builtin_amdgcn_mfma_f32_16x16x32_bf16(
                    aF[mi], bF[ni], acc[mi][ni], 0, 0, 0);
        __builtin_amdgcn_s_setprio(0);
    }

    // epilogue: exp + row sums (always) + col sums (off-diag symmetry)
    const bool offdiag = (tm != tn);
    float colsum[4] = {0.f, 0.f, 0.f, 0.f};
#pragma unroll
    for (int q = 0; q < 8; ++q) {
#pragma unroll
        for (int r = 0; r < 4; ++r) {
            float rs = 0.0f;
#pragma unroll
            for (int ni = 0; ni < 4; ++ni) {
                float e = __expf(2.0f * acc[q][ni][r]);
                rs += e;
                colsum[ni] += e;
            }
            rs += __shfl_xor(rs, 1);
            rs += __shfl_xor(rs, 2);
            rs += __shfl_xor(rs, 4);
            rs += __shfl_xor(rs, 8);
            if (lr == 0) {
                size_t row = rowA + wr + q * 16 + lh * 4 + r;
                atomicAdd(&S[row], rs);
            }
        }
    }
    if (offdiag) {
#pragma unroll
        for (int ni = 0; ni < 4; ++ni) {
            float cs = colsum[ni];
            cs += __shfl_xor(cs, 16);
            cs += __shfl_xor(cs, 32);
            if (lh == 0) {
                size_t col = rowB + wc + ni * 16 + lr;
                atomicAdd(&S[col], cs);
            }
        }
    }
}

// fused: row-normalize rows i and i+NS of M (in place, bf16 RNE) and
// g12[i] = dot of the ROUNDED normalized rows (numerics == split kernels).
// 8192 blocks.
__global__ __launch_bounds__(256) void normdiag_kernel(u16* M, float* g12) {
    __shared__ float red[12];
    const int tid = threadIdx.x;
    u16* r1 = M + ((size_t)blockIdx.x << 10);
    u16* r2 = r1 + ((size_t)NS << 10);
    ushort4 va = ((const ushort4*)r1)[tid];
    ushort4 vb = ((const ushort4*)r2)[tid];
    float a0 = bf2f(va.x), a1 = bf2f(va.y), a2 = bf2f(va.z), a3 = bf2f(va.w);
    float b0 = bf2f(vb.x), b1 = bf2f(vb.y), b2 = bf2f(vb.z), b3 = bf2f(vb.w);
    float s1 = a0 * a0 + a1 * a1 + a2 * a2 + a3 * a3;
    float s2 = b0 * b0 + b1 * b1 + b2 * b2 + b3 * b3;
#pragma unroll
    for (int m = 1; m < 64; m <<= 1) {
        s1 += __shfl_xor(s1, m);
        s2 += __shfl_xor(s2, m);
    }
    const int w = tid >> 6;
    if ((tid & 63) == 0) { red[w] = s1; red[4 + w] = s2; }
    __syncthreads();
    float inv1 = rsqrtf(red[0] + red[1] + red[2] + red[3]);
    float inv2 = rsqrtf(red[4] + red[5] + red[6] + red[7]);
    ushort4 oa, ob;
    oa.x = f2bf(a0 * inv1); oa.y = f2bf(a1 * inv1);
    oa.z = f2bf(a2 * inv1); oa.w = f2bf(a3 * inv1);
    ob.x = f2bf(b0 * inv2); ob.y = f2bf(b1 * inv2);
    ob.z = f2bf(b2 * inv2); ob.w = f2bf(b3 * inv2);
    ((ushort4*)r1)[tid] = oa;
    ((ushort4*)r2)[tid] = ob;
    // dot of rounded values (matches old diag_kernel reading rounded H)
    float d = bf2f(oa.x) * bf2f(ob.x) + bf2f(oa.y) * bf2f(ob.y) +
              bf2f(oa.z) * bf2f(ob.z) + bf2f(oa.w) * bf2f(ob.w);
#pragma unroll
    for (int m = 1; m < 64; m <<= 1) d += __shfl_xor(d, m);
    if ((tid & 63) == 0) red[8 + w] = d;
    __syncthreads();
    if (tid == 0) g12[blockIdx.x] = red[8] + red[9] + red[10] + red[11];
}

__global__ __launch_bounds__(256) void final_kernel(const float* Sr, const float* Sc,
                                                    const float* gr, const float* gc,
                                                    const float* w_r1, float* out) {
    __shared__ float red[16];
    const float E2 = 7.389056098930650f;  // exp(1/tau), tau=0.5
    float a = 0.f, b = 0.f, c = 0.f, d = 0.f;
    for (int i = threadIdx.x; i < 2 * NS; i += 256) {
        a += logf(Sr[i] - E2);
        b += logf(Sc[i] - E2);
    }
    for (int i = threadIdx.x; i < NS; i += 256) {
        c += gr[i];
        d += gc[i];
    }
#pragma unroll
    for (int m = 1; m < 64; m <<= 1) {
        a += __shfl_xor(a, m); b += __shfl_xor(b, m);
        c += __shfl_xor(c, m); d += __shfl_xor(d, m);
    }
    int w = threadIdx.x >> 6;
    if ((threadIdx.x & 63) == 0) {
        red[w] = a; red[4 + w] = b; red[8 + w] = c; red[12 + w] = d;
    }
    __syncthreads();
    if (threadIdx.x == 0) {
        a = red[0] + red[1] + red[2] + red[3];
        b = red[4] + red[5] + red[6] + red[7];
        c = red[8] + red[9] + red[10] + red[11];
        d = red[12] + red[13] + red[14] + red[15];
        float lr = a / (2.0f * NS) - 2.0f * c / NS;
        float lc = b / (2.0f * NS) - 2.0f * d / NS;
        float w0 = w_r1[0];
        w0 = fminf(fmaxf(w0, 0.0f), 1.0f);
        out[0] = w0 * lr + (1.0f - w0) * lc;
    }
}

extern "C" void kernel_launch(void* const* d_in, const int* in_sizes, int n_in,
                              void* d_out, int out_size, void* d_ws, size_t ws_size,
                              hipStream_t stream) {
    const float* ta = (const float*)d_in[0];
    const float* tb = (const float*)d_in[1];
    const float* W1 = (const float*)d_in[2];
    const float* b1 = (const float*)d_in[3];
    const float* W2 = (const float*)d_in[4];
    const float* b2 = (const float*)d_in[5];
    const float* W3 = (const float*)d_in[6];
    const float* b3 = (const float*)d_in[7];
    const float* W4 = (const float*)d_in[8];
    const float* b4 = (const float*)d_in[9];
    const float* wr = (const float*)d_in[10];
    float* out = (float*)d_out;

    char* p = (char*)d_ws;
    const size_t MAT = (size_t)2 * NS * DD * sizeof(u16);  // 33.5 MB
    u16* Z = (u16*)p;  p += MAT;    // row-view input; later holds Hc
    u16* T = (u16*)p;  p += MAT;
    u16* H = (u16*)p;  p += MAT;    // Hr
    u16* Wb = (u16*)p; p += (size_t)4 * DD * DD * sizeof(u16);
    float* Sr = (float*)p;  p += 2 * NS * sizeof(float);
    float* Sc = (float*)p;  p += 2 * NS * sizeof(float);
    float* gr = (float*)p;  p += NS * sizeof(float);
    float* gc = (float*)p;  p += NS * sizeof(float);

    u16* Wb1 = Wb;
    u16* Wb2 = Wb + (size_t)DD * DD;
    u16* Wb3 = Wb + (size_t)2 * DD * DD;
    u16* Wb4 = Wb + (size_t)3 * DD * DD;

    conv_f2bf4<<<4096, 256, 0, stream>>>(W1, W2, W3, W4, Wb);
    hipMemsetAsync(Sr, 0, 4 * NS * sizeof(float), stream);  // Sr and Sc contiguous

    // ---- row view projection: Hr = H ----
    conv_cat<<<16384, 256, 0, stream>>>(ta, tb, Z);
    gemm_bt<0><<<dim3(8, 128), 256, 0, stream>>>(Z, Wb1, b1, T);   // Z free after
    gemm_bt<1><<<dim3(8, 128), 256, 0, stream>>>(T, Wb2, b2, H);
    normdiag_kernel<<<8192, 256, 0, stream>>>(H, gr);

    // ---- col view projection: Hc = Z (reuses freed buffer) ----
    conv_col<<<16384, 256, 0, stream>>>(ta, tb, Z);
    gemm_bt<0><<<dim3(8, 128), 256, 0, stream>>>(Z, Wb3, b3, T);
    gemm_bt<1><<<dim3(8, 128), 256, 0, stream>>>(T, Wb4, b4, Z);
    normdiag_kernel<<<8192, 256, 0, stream>>>(Z, gc);

    // ---- both Grams in one dispatch (4160 blocks, R4 internals) ----
    gram256<<<dim3(65, 64), 512, 0, stream>>>(H, Z, Sr);

    final_kernel<<<1, 256, 0, stream>>>(Sr, Sc, gr, gc, wr, out);
}

// Round 13
// 1084.836 us; speedup vs baseline: 2.3225x; 1.0356x over previous
//
#include <hip/hip_runtime.h>
#include <stdint.h>

// ---------------------------------------------------------------------------
// TContrastive: GRACE InfoNCE loss.
//   loss_view = (1/2N) sum_i log(S_i - e^2) - (2/N) sum_i g12_i
// where S = row sums of exp(2 * M M^T), M = [n1; n2] row-normalized (16384x1024).
// Heavy GEMMs in bf16 MFMA (16x16x32), fp32 accumulate. tau = 0.5.
// R1: Gram symmetry — triangle tiles only; off-diag adds row+col exp-sums.
// R2-R11: gram structural plateau ~680-715 TF; R4 ring-4/1-barrier/counted-
//   vmcnt structure best. Falsified: read swizzles, XCD remap, 4/8-phase,
//   32x32-in-8wave, multi-block residency, NO-LDS.
// R12 (kept): merged both view-grams into one dispatch (tail once, -45us);
//   fused normalize+diag; batched weight conversion. 1123.5us, absmax 0.
// R13: fc GEMMs ported onto the gram's ring-4 256^2 skeleton (identical
//   staging + K-loop; epilogue = bias+ELU+bf16 store). fc shape M=16384,
//   N=1024 -> grid 4x64 = 256 blocks = exactly 1/CU, zero tail. Same
//   ascending-k0 accumulation -> bitwise-identical fc outputs.
// ---------------------------------------------------------------------------

typedef unsigned short u16;
typedef __attribute__((ext_vector_type(8))) __bf16 bf16x8;
typedef __attribute__((ext_vector_type(4))) float f32x4;

#define NS 8192       // samples per view half
#define DD 1024       // feature dim

__device__ __forceinline__ float bf2f(u16 u) {
    union { uint32_t i; float f; } v; v.i = ((uint32_t)u) << 16; return v.f;
}
__device__ __forceinline__ u16 f2bf(float f) {
    union { float f; uint32_t i; } v; v.f = f;
    return (u16)((v.i + 0x7FFFu + ((v.i >> 16) & 1u)) >> 16);   // RNE
}

// async global->LDS, 16B per lane. LDS dest must be wave-uniform-base + lane*16.
__device__ __forceinline__ void gload16(const u16* g, u16* l) {
    __builtin_amdgcn_global_load_lds(
        (__attribute__((address_space(1))) void*)(uintptr_t)(g),
        (__attribute__((address_space(3))) void*)(uintptr_t)(l), 16, 0, 0);
}

// ---------------- elementwise conversion kernels ----------------

// all 4 weight matrices in one launch: 4096 blocks, 1024 floats each
__global__ __launch_bounds__(256) void conv_f2bf4(const float* __restrict__ W1,
                                                  const float* __restrict__ W2,
                                                  const float* __restrict__ W3,
                                                  const float* __restrict__ W4,
                                                  u16* __restrict__ dst) {
    const int b = blockIdx.x;                 // [0,4096)
    const float* src = (b < 1024) ? W1 : (b < 2048) ? W2 : (b < 3072) ? W3 : W4;
    const size_t so = ((size_t)(b & 1023) << 10) + threadIdx.x * 4;
    const size_t doo = ((size_t)b << 10) + threadIdx.x * 4;
    float4 v = *(const float4*)(src + so);
    ushort4 o;
    o.x = f2bf(v.x); o.y = f2bf(v.y); o.z = f2bf(v.z); o.w = f2bf(v.w);
    *(ushort4*)(dst + doo) = o;
}

// Z = bf16([ta; tb]) row view (16384x1024), 16384 blocks
__global__ __launch_bounds__(256) void conv_cat(const float* __restrict__ a,
                                                const float* __restrict__ b,
                                                u16* __restrict__ Z) {
    size_t i = (size_t)(blockIdx.x * 256 + threadIdx.x) * 4;
    const size_t half = (size_t)NS * DD;
    const float* s = (i < half) ? (a + i) : (b + (i - half));
    float4 v = *(const float4*)s;
    ushort4 o;
    o.x = f2bf(v.x); o.y = f2bf(v.y); o.z = f2bf(v.z); o.w = f2bf(v.w);
    *(ushort4*)(Z + i) = o;
}

// column view: Z[i, b*32+a] = src[i, a*32+b]  (per-row 32x32 transpose)
__global__ __launch_bounds__(256) void conv_col(const float* __restrict__ a,
                                                const float* __restrict__ b,
                                                u16* __restrict__ Z) {
    size_t i = (size_t)(blockIdx.x * 256 + threadIdx.x) * 4;
    const size_t half = (size_t)NS * DD;
    const float* src; size_t o;
    if (i < half) { src = a; o = i; } else { src = b; o = i - half; }
    size_t row = o >> 10;
    int j = (int)(o & 1023);
    int aI = j & 31, bI = j >> 5;      // j = b*32 + a
    const float* rp = src + (row << 10);
    ushort4 ov;
    ov.x = f2bf(rp[aI * 32 + bI]);
    ov.y = f2bf(rp[(aI + 1) * 32 + bI]);
    ov.z = f2bf(rp[(aI + 2) * 32 + bI]);
    ov.w = f2bf(rp[(aI + 3) * 32 + bI]);
    *(ushort4*)(Z + i) = ov;
}

// ---------------- fc GEMM: ring-4 256^2 skeleton (gram-proven) ----------
// C[m,n] = sum_k A[m,k] * B[n,k]; out = bf16(MODE 0 ? elu(C+bias) : C+bias).
// Grid dim3(4, 64) = 256 blocks = exactly 1/CU. 8 waves (2Mx4N), BK=32,
// 4-deep LDS ring, one barrier per K-tile, counted vmcnt.
template <int MODE>
__global__ __launch_bounds__(512, 2) void gemm256_bt(const u16* __restrict__ A,
                                                     const u16* __restrict__ B,
                                                     const float* __restrict__ bias,
                                                     u16* __restrict__ out) {
    __shared__ alignas(16) u16 LA[4][256 * 32];
    __shared__ alignas(16) u16 LB[4][256 * 32];
    const int tid = threadIdx.x;

    const size_t rowA = (size_t)blockIdx.y * 256;   // tileM
    const size_t rowB = (size_t)blockIdx.x * 256;   // tileN

    const int r_lo = tid >> 2;                      // 0..127
    const int csw  = ((tid & 3) ^ ((r_lo >> 2) & 3)) * 8;
    const u16* gA0 = A + (rowA + r_lo) * DD + csw;
    const u16* gA1 = A + (rowA + 128 + r_lo) * DD + csw;
    const u16* gB0 = B + (rowB + r_lo) * DD + csw;
    const u16* gB1 = B + (rowB + 128 + r_lo) * DD + csw;
    const int ldst = tid * 8;

    const int lane = tid & 63;
    const int wv = tid >> 6;
    const int wr = (wv >> 2) * 128;          // wave row offset: 0 / 128
    const int wc = (wv & 3) * 64;            // wave col offset: 0/64/128/192
    const int lr = lane & 15;
    const int lh = lane >> 4;
    const int sw = lh ^ ((lr >> 2) & 3);
    const int aoff = (wr + lr) * 32 + sw * 8;
    const int boff = (wc + lr) * 32 + sw * 8;

    f32x4 acc[8][4];
#pragma unroll
    for (int i = 0; i < 8; ++i)
#pragma unroll
        for (int j = 0; j < 4; ++j) acc[i][j] = (f32x4)0.0f;

#pragma unroll
    for (int t = 0; t < 3; ++t) {
        const int k0 = t * 32;
        gload16(gA0 + k0, &LA[t][0] + ldst);
        gload16(gA1 + k0, &LA[t][4096] + ldst);
        gload16(gB0 + k0, &LB[t][0] + ldst);
        gload16(gB1 + k0, &LB[t][4096] + ldst);
    }

    for (int t = 0; t < 32; ++t) {
        if (t < 30)       asm volatile("s_waitcnt vmcnt(8)" ::: "memory");
        else if (t == 30) asm volatile("s_waitcnt vmcnt(4)" ::: "memory");
        else              asm volatile("s_waitcnt vmcnt(0)" ::: "memory");
        __builtin_amdgcn_s_barrier();
        asm volatile("" ::: "memory");

        const int buf = t & 3;
        const u16* la = &LA[buf][0];
        const u16* lb = &LB[buf][0];

        bf16x8 bF[4], aF[8];
#pragma unroll
        for (int i = 0; i < 4; ++i) bF[i] = *(const bf16x8*)(lb + boff + i * 512);
#pragma unroll
        for (int i = 0; i < 8; ++i) aF[i] = *(const bf16x8*)(la + aoff + i * 512);

        if (t < 29) {
            const int nbuf = (t + 3) & 3;
            const int k0n = (t + 3) * 32;
            gload16(gA0 + k0n, &LA[nbuf][0] + ldst);
            gload16(gA1 + k0n, &LA[nbuf][4096] + ldst);
            gload16(gB0 + k0n, &LB[nbuf][0] + ldst);
            gload16(gB1 + k0n, &LB[nbuf][4096] + ldst);
        }

        __builtin_amdgcn_s_setprio(1);
#pragma unroll
        for (int mi = 0; mi < 8; ++mi)
#pragma unroll
            for (int ni = 0; ni < 4; ++ni)
                acc[mi][ni] = __builtin_amdgcn_mfma_f32_16x16x32_bf16(
                    aF[mi], bF[ni], acc[mi][ni], 0, 0, 0);
        __builtin_amdgcn_s_setprio(0);
    }

    // epilogue: bias + (ELU) + bf16 store. C layout: col = lane&15 (lr),
    // row-in-tile = lh*4 + r; tile (mi, ni) at rows wr+mi*16, cols wc+ni*16.
    float bcol[4];
#pragma unroll
    for (int ni = 0; ni < 4; ++ni) bcol[ni] = bias[rowB + wc + ni * 16 + lr];
#pragma unroll
    for (int q = 0; q < 8; ++q) {
#pragma unroll
        for (int r = 0; r < 4; ++r) {
            size_t row = rowA + wr + q * 16 + lh * 4 + r;
            u16* orow = out + row * DD + rowB + wc + lr;
#pragma unroll
            for (int ni = 0; ni < 4; ++ni) {
                float v = acc[q][ni][r] + bcol[ni];
                if (MODE == 0) v = v > 0.0f ? v : expm1f(v);
                orow[ni * 16] = f2bf(v);
            }
        }
    }
}

// ---------------- Merged Gram kernel: R4 internals, both views -----------
// 256^2 tiles, 8 waves, BK=32, 4-deep LDS ring, one barrier per K-tile,
// counted vmcnt, 16x16x32 MFMA. Grid dim3(65, 64): y<32 = row view
// (Hr -> Sbase), y>=32 = col view (Hc -> Sbase+2NS). 4160 blocks total.
__global__ __launch_bounds__(512, 2) void gram256(const u16* __restrict__ Hr,
                                                  const u16* __restrict__ Hc,
                                                  float* __restrict__ Sbase) {
    __shared__ alignas(16) u16 LA[4][256 * 32];
    __shared__ alignas(16) u16 LB[4][256 * 32];
    const int tid = threadIdx.x;

    const int view = (int)blockIdx.y >> 5;
    const u16* H = view ? Hc : Hr;
    float* S = Sbase + view * 2 * NS;
    int x = blockIdx.x, y = (int)blockIdx.y & 31;   // x in [0,65), y in [0,32)
    int tm, tn;
    if (y + x < 64) { tm = y;      tn = y + x; }
    else            { tm = 63 - y; tn = x - 1; }

    const size_t rowA = (size_t)tm * 256;
    const size_t rowB = (size_t)tn * 256;

    const int r_lo = tid >> 2;                      // 0..127
    const int csw  = ((tid & 3) ^ ((r_lo >> 2) & 3)) * 8;
    const u16* gA0 = H + (rowA + r_lo) * DD + csw;
    const u16* gA1 = H + (rowA + 128 + r_lo) * DD + csw;
    const u16* gB0 = H + (rowB + r_lo) * DD + csw;
    const u16* gB1 = H + (rowB + 128 + r_lo) * DD + csw;
    const int ldst = tid * 8;                       // u16 offset of chunk

    const int lane = tid & 63;
    const int wv = tid >> 6;
    const int wr = (wv >> 2) * 128;          // wave row offset: 0 / 128
    const int wc = (wv & 3) * 64;            // wave col offset: 0/64/128/192
    const int lr = lane & 15;
    const int lh = lane >> 4;
    const int sw = lh ^ ((lr >> 2) & 3);     // swizzled read slot
    const int aoff = (wr + lr) * 32 + sw * 8;
    const int boff = (wc + lr) * 32 + sw * 8;

    f32x4 acc[8][4];
#pragma unroll
    for (int i = 0; i < 8; ++i)
#pragma unroll
        for (int j = 0; j < 4; ++j) acc[i][j] = (f32x4)0.0f;

#pragma unroll
    for (int t = 0; t < 3; ++t) {
        const int k0 = t * 32;
        gload16(gA0 + k0, &LA[t][0] + ldst);
        gload16(gA1 + k0, &LA[t][4096] + ldst);
        gload16(gB0 + k0, &LB[t][0] + ldst);
        gload16(gB1 + k0, &LB[t][4096] + ldst);
    }

    for (int t = 0; t < 32; ++t) {
        if (t < 30)       asm volatile("s_waitcnt vmcnt(8)" ::: "memory");
        else if (t == 30) asm volatile("s_waitcnt vmcnt(4)" ::: "memory");
        else              asm volatile("s_waitcnt vmcnt(0)" ::: "memory");
        __builtin_amdgcn_s_barrier();
        asm volatile("" ::: "memory");       // pin ds_reads after barrier

        const int buf = t & 3;
        const u16* la = &LA[buf][0];
        const u16* lb = &LB[buf][0];

        bf16x8 bF[4], aF[8];
#pragma unroll
        for (int i = 0; i < 4; ++i) bF[i] = *(const bf16x8*)(lb + boff + i * 512);
#pragma unroll
        for (int i = 0; i < 8; ++i) aF[i] = *(const bf16x8*)(la + aoff + i * 512);

        if (t < 29) {
            const int nbuf = (t + 3) & 3;
            const int k0n = (t + 3) * 32;
            gload16(gA0 + k0n, &LA[nbuf][0] + ldst);
            gload16(gA1 + k0n, &LA[nbuf][4096] + ldst);
            gload16(gB0 + k0n, &LB[nbuf][0] + ldst);
            gload16(gB1 + k0n, &LB[nbuf][4096] + ldst);
        }

        __builtin_amdgcn_s_setprio(1);
#pragma unroll
        for (int mi = 0; mi < 8; ++mi)       // cluster mi gated when aF[mi] lands
#pragma unroll
            for (int ni = 0; ni < 4; ++ni)
                acc[mi][ni] = __builtin_amdgcn_mfma_f32_16x16x32_bf16(
                    aF[mi], bF[ni], acc[mi][ni], 0, 0, 0);
        __builtin_amdgcn_s_setprio(0);
    }

    // epilogue: exp + row sums (always) + col sums (off-diag symmetry)
    const bool offdiag = (tm != tn);
    float colsum[4] = {0.f, 0.f, 0.f, 0.f};
#pragma unroll
    for (int q = 0; q < 8; ++q) {
#pragma unroll
        for (int r = 0; r < 4; ++r) {
            float rs = 0.0f;
#pragma unroll
            for (int ni = 0; ni < 4; ++ni) {
                float e = __expf(2.0f * acc[q][ni][r]);
                rs += e;
                colsum[ni] += e;
            }
            rs += __shfl_xor(rs, 1);
            rs += __shfl_xor(rs, 2);
            rs += __shfl_xor(rs, 4);
            rs += __shfl_xor(rs, 8);
            if (lr == 0) {
                size_t row = rowA + wr + q * 16 + lh * 4 + r;
                atomicAdd(&S[row], rs);
            }
        }
    }
    if (offdiag) {
#pragma unroll
        for (int ni = 0; ni < 4; ++ni) {
            float cs = colsum[ni];
            cs += __shfl_xor(cs, 16);
            cs += __shfl_xor(cs, 32);
            if (lh == 0) {
                size_t col = rowB + wc + ni * 16 + lr;
                atomicAdd(&S[col], cs);
            }
        }
    }
}

// fused: row-normalize rows i and i+NS of M (in place, bf16 RNE) and
// g12[i] = dot of the ROUNDED normalized rows. 8192 blocks.
__global__ __launch_bounds__(256) void normdiag_kernel(u16* M, float* g12) {
    __shared__ float red[12];
    const int tid = threadIdx.x;
    u16* r1 = M + ((size_t)blockIdx.x << 10);
    u16* r2 = r1 + ((size_t)NS << 10);
    ushort4 va = ((const ushort4*)r1)[tid];
    ushort4 vb = ((const ushort4*)r2)[tid];
    float a0 = bf2f(va.x), a1 = bf2f(va.y), a2 = bf2f(va.z), a3 = bf2f(va.w);
    float b0 = bf2f(vb.x), b1 = bf2f(vb.y), b2 = bf2f(vb.z), b3 = bf2f(vb.w);
    float s1 = a0 * a0 + a1 * a1 + a2 * a2 + a3 * a3;
    float s2 = b0 * b0 + b1 * b1 + b2 * b2 + b3 * b3;
#pragma unroll
    for (int m = 1; m < 64; m <<= 1) {
        s1 += __shfl_xor(s1, m);
        s2 += __shfl_xor(s2, m);
    }
    const int w = tid >> 6;
    if ((tid & 63) == 0) { red[w] = s1; red[4 + w] = s2; }
    __syncthreads();
    float inv1 = rsqrtf(red[0] + red[1] + red[2] + red[3]);
    float inv2 = rsqrtf(red[4] + red[5] + red[6] + red[7]);
    ushort4 oa, ob;
    oa.x = f2bf(a0 * inv1); oa.y = f2bf(a1 * inv1);
    oa.z = f2bf(a2 * inv1); oa.w = f2bf(a3 * inv1);
    ob.x = f2bf(b0 * inv2); ob.y = f2bf(b1 * inv2);
    ob.z = f2bf(b2 * inv2); ob.w = f2bf(b3 * inv2);
    ((ushort4*)r1)[tid] = oa;
    ((ushort4*)r2)[tid] = ob;
    float d = bf2f(oa.x) * bf2f(ob.x) + bf2f(oa.y) * bf2f(ob.y) +
              bf2f(oa.z) * bf2f(ob.z) + bf2f(oa.w) * bf2f(ob.w);
#pragma unroll
    for (int m = 1; m < 64; m <<= 1) d += __shfl_xor(d, m);
    if ((tid & 63) == 0) red[8 + w] = d;
    __syncthreads();
    if (tid == 0) g12[blockIdx.x] = red[8] + red[9] + red[10] + red[11];
}

__global__ __launch_bounds__(256) void final_kernel(const float* Sr, const float* Sc,
                                                    const float* gr, const float* gc,
                                                    const float* w_r1, float* out) {
    __shared__ float red[16];
    const float E2 = 7.389056098930650f;  // exp(1/tau), tau=0.5
    float a = 0.f, b = 0.f, c = 0.f, d = 0.f;
    for (int i = threadIdx.x; i < 2 * NS; i += 256) {
        a += logf(Sr[i] - E2);
        b += logf(Sc[i] - E2);
    }
    for (int i = threadIdx.x; i < NS; i += 256) {
        c += gr[i];
        d += gc[i];
    }
#pragma unroll
    for (int m = 1; m < 64; m <<= 1) {
        a += __shfl_xor(a, m); b += __shfl_xor(b, m);
        c += __shfl_xor(c, m); d += __shfl_xor(d, m);
    }
    int w = threadIdx.x >> 6;
    if ((threadIdx.x & 63) == 0) {
        red[w] = a; red[4 + w] = b; red[8 + w] = c; red[12 + w] = d;
    }
    __syncthreads();
    if (threadIdx.x == 0) {
        a = red[0] + red[1] + red[2] + red[3];
        b = red[4] + red[5] + red[6] + red[7];
        c = red[8] + red[9] + red[10] + red[11];
        d = red[12] + red[13] + red[14] + red[15];
        float lr = a / (2.0f * NS) - 2.0f * c / NS;
        float lc = b / (2.0f * NS) - 2.0f * d / NS;
        float w0 = w_r1[0];
        w0 = fminf(fmaxf(w0, 0.0f), 1.0f);
        out[0] = w0 * lr + (1.0f - w0) * lc;
    }
}

extern "C" void kernel_launch(void* const* d_in, const int* in_sizes, int n_in,
                              void* d_out, int out_size, void* d_ws, size_t ws_size,
                              hipStream_t stream) {
    const float* ta = (const float*)d_in[0];
    const float* tb = (const float*)d_in[1];
    const float* W1 = (const float*)d_in[2];
    const float* b1 = (const float*)d_in[3];
    const float* W2 = (const float*)d_in[4];
    const float* b2 = (const float*)d_in[5];
    const float* W3 = (const float*)d_in[6];
    const float* b3 = (const float*)d_in[7];
    const float* W4 = (const float*)d_in[8];
    const float* b4 = (const float*)d_in[9];
    const float* wr = (const float*)d_in[10];
    float* out = (float*)d_out;

    char* p = (char*)d_ws;
    const size_t MAT = (size_t)2 * NS * DD * sizeof(u16);  // 33.5 MB
    u16* Z = (u16*)p;  p += MAT;    // row-view input; later holds Hc
    u16* T = (u16*)p;  p += MAT;
    u16* H = (u16*)p;  p += MAT;    // Hr
    u16* Wb = (u16*)p; p += (size_t)4 * DD * DD * sizeof(u16);
    float* Sr = (float*)p;  p += 2 * NS * sizeof(float);
    float* Sc = (float*)p;  p += 2 * NS * sizeof(float);
    float* gr = (float*)p;  p += NS * sizeof(float);
    float* gc = (float*)p;  p += NS * sizeof(float);

    u16* Wb1 = Wb;
    u16* Wb2 = Wb + (size_t)DD * DD;
    u16* Wb3 = Wb + (size_t)2 * DD * DD;
    u16* Wb4 = Wb + (size_t)3 * DD * DD;

    conv_f2bf4<<<4096, 256, 0, stream>>>(W1, W2, W3, W4, Wb);
    hipMemsetAsync(Sr, 0, 4 * NS * sizeof(float), stream);  // Sr and Sc contiguous

    // ---- row view projection: Hr = H ----
    conv_cat<<<16384, 256, 0, stream>>>(ta, tb, Z);
    gemm256_bt<0><<<dim3(4, 64), 512, 0, stream>>>(Z, Wb1, b1, T);  // Z free after
    gemm256_bt<1><<<dim3(4, 64), 512, 0, stream>>>(T, Wb2, b2, H);
    normdiag_kernel<<<8192, 256, 0, stream>>>(H, gr);

    // ---- col view projection: Hc = Z (reuses freed buffer) ----
    conv_col<<<16384, 256, 0, stream>>>(ta, tb, Z);
    gemm256_bt<0><<<dim3(4, 64), 512, 0, stream>>>(Z, Wb3, b3, T);
    gemm256_bt<1><<<dim3(4, 64), 512, 0, stream>>>(T, Wb4, b4, Z);
    normdiag_kernel<<<8192, 256, 0, stream>>>(Z, gc);

    // ---- both Grams in one dispatch (4160 blocks, R4 internals) ----
    gram256<<<dim3(65, 64), 512, 0, stream>>>(H, Z, Sr);

    final_kernel<<<1, 256, 0, stream>>>(Sr, Sc, gr, gc, wr, out);
}